// Round 2
// baseline (1064.197 us; speedup 1.0000x reference)
//
#include <hip/hip_runtime.h>
#include <hip/hip_bf16.h>
#include <stdint.h>

// GCN1: x3 = adj@(x2@W3)+b3; x2 = adj@(x1@W2)+b2; x1 = drop(relu(adj@(x@W1)+b1))
// bf16 MFMA GEMMs (2% rel tolerance), exact JAX threefry dropout.
// R2: split-K for the three adj GEMMs.
// R3: 256x256 8-wave pipelined GEMM for the two big adj GEMMs.
// R4: fix R3's wait/consumption mismatch (waves consume ALL M-halves at phase 0,
//     so per-half counted waits were racy): clustered 8-load prefetch + single
//     WAITV(8) per K-tile (prefetch spans all 4 compute phases), 5 barriers/tile.

#define MROWS 10000
#define KPAD  10048   // 10000 padded to multiple of 64 (157 BK=64 tiles)

typedef __attribute__((ext_vector_type(8))) short short8;
typedef __attribute__((ext_vector_type(4))) float floatx4;

__device__ __forceinline__ unsigned short f2bf(float f) {
  union { float f; unsigned u; } v; v.f = f;
  unsigned u = v.u;
  u += 0x7fffu + ((u >> 16) & 1u);   // round-to-nearest-even
  return (unsigned short)(u >> 16);
}

// ---- exact JAX threefry2x32-20, key(42) = (0, 42), iota split in halves ----
__device__ __forceinline__ bool dropout_keep(unsigned i) {
  const unsigned halfn = 2560000u;           // (10000*512)/2
  const unsigned j = (i < halfn) ? i : (i - halfn);
  unsigned x0 = j, x1 = j + halfn;
  const unsigned k0 = 0u, k1 = 42u, k2 = 0u ^ 42u ^ 0x1BD11BDAu;
  x0 += k0; x1 += k1;
#define TFR(r) { x0 += x1; x1 = (x1 << (r)) | (x1 >> (32 - (r))); x1 ^= x0; }
  TFR(13) TFR(15) TFR(26) TFR(6)   x0 += k1; x1 += k2 + 1u;
  TFR(17) TFR(29) TFR(16) TFR(24)  x0 += k2; x1 += k0 + 2u;
  TFR(13) TFR(15) TFR(26) TFR(6)   x0 += k0; x1 += k1 + 3u;
  TFR(17) TFR(29) TFR(16) TFR(24)  x0 += k1; x1 += k2 + 4u;
  TFR(13) TFR(15) TFR(26) TFR(6)   x0 += k2; x1 += k0 + 5u;
#undef TFR
  const unsigned bits = (i < halfn) ? x0 : x1;
  return bits < 0x80000000u;   // uniform(bits) < 0.5, exact transform
}

// ---- cast kernels ----
__global__ void cast_adj_kernel(const float* __restrict__ in, unsigned short* __restrict__ out) {
  const int q = blockIdx.x * blockDim.x + threadIdx.x;  // quad of 4 cols
  const int row = blockIdx.y;
  if (q >= 2512) return;                                 // 10048/4
  const int col = q * 4;
  ushort4 o;
  if (col < 10000) {
    const float4 v = *(const float4*)(in + (size_t)row * 10000 + col);
    o.x = f2bf(v.x); o.y = f2bf(v.y); o.z = f2bf(v.z); o.w = f2bf(v.w);
  } else {
    o.x = 0; o.y = 0; o.z = 0; o.w = 0;                  // K-pad zeros
  }
  *(ushort4*)(out + (size_t)row * KPAD + col) = o;
}

__global__ void cast_vec_kernel(const float* __restrict__ in, unsigned short* __restrict__ out, int n4) {
  const int id = blockIdx.x * blockDim.x + threadIdx.x;
  if (id >= n4) return;
  const float4 v = ((const float4*)in)[id];
  ushort4 o; o.x = f2bf(v.x); o.y = f2bf(v.y); o.z = f2bf(v.z); o.w = f2bf(v.w);
  ((ushort4*)out)[id] = o;
}

// W (K x N) f32 -> W^T (N x K) bf16
__global__ void castT_kernel(const float* __restrict__ in, unsigned short* __restrict__ out, int K, int N) {
  const int id = blockIdx.x * blockDim.x + threadIdx.x;
  if (id >= K * N) return;
  const int n = id / K, k = id % K;
  out[(size_t)n * K + k] = f2bf(in[(size_t)k * N + n]);
}

// zero pad cols 10000..10048 of an (rows x KPAD) buffer
__global__ void zero_pad_kernel(unsigned short* __restrict__ p, int rows) {
  const int id = blockIdx.x * blockDim.x + threadIdx.x;
  if (id >= rows * 48) return;
  const int r = id / 48, c = id % 48;
  p[(size_t)r * KPAD + 10000 + c] = 0;
}

// ---- bf16 MFMA GEMM (legacy 128x128): C = A(MxK) @ BT'(KxN) ----
// OUT_KIND: 0 = bf16 transposed store (C^T, ldc = row stride of C^T)
//           1 = bf16 row-major, 2 = f32 row-major,
//           3 = f32 partial (split-K): P[z*M*N + row*N + col] = acc  (no bias)
// EPI: 0 none, 1 +bias, 2 +bias,relu,dropout(x2)
template<int OUT_KIND, int EPI>
__global__ __launch_bounds__(256, 2) void gemm_mfma(
    const unsigned short* __restrict__ A, int lda,
    const unsigned short* __restrict__ BT, int ldb,
    void* __restrict__ Cv, int ldc,
    const float* __restrict__ bias,
    int M, int N, int K,
    int chunk)
{
  __shared__ unsigned short As[128 * 32];
  __shared__ unsigned short Bs[128 * 32];

  const int tid  = threadIdx.x;
  const int lane = tid & 63;
  const int wave = tid >> 6;
  const int m0 = blockIdx.y * 128;
  const int n0 = blockIdx.x * 128;
  const int wm = (wave & 1) * 64;
  const int wn = (wave >> 1) * 64;

  int kstart = 0, kend = K;
  if (OUT_KIND == 3) {
    kstart = blockIdx.z * chunk;
    kend   = kstart + chunk; if (kend > K) kend = K;
  }

  floatx4 acc[4][4];
#pragma unroll
  for (int i = 0; i < 4; ++i)
#pragma unroll
    for (int j = 0; j < 4; ++j) acc[i][j] = (floatx4){0.f, 0.f, 0.f, 0.f};

  const int c1 = tid, c2 = tid + 256;
  int ar1 = m0 + (c1 >> 2); if (ar1 > M - 1) ar1 = M - 1;
  int ar2 = m0 + (c2 >> 2); if (ar2 > M - 1) ar2 = M - 1;
  const int br1 = n0 + (c1 >> 2);
  const int br2 = n0 + (c2 >> 2);
  const unsigned short* aG1 = A  + (size_t)ar1 * lda + (c1 & 3) * 8;
  const unsigned short* aG2 = A  + (size_t)ar2 * lda + (c2 & 3) * 8;
  const unsigned short* bG1 = BT + (size_t)br1 * ldb + (c1 & 3) * 8;
  const unsigned short* bG2 = BT + (size_t)br2 * ldb + (c2 & 3) * 8;
  unsigned short* lA1 = As + c1 * 8;
  unsigned short* lA2 = As + c2 * 8;
  unsigned short* lB1 = Bs + c1 * 8;
  unsigned short* lB2 = Bs + c2 * 8;

  const int fr = lane & 15;
  const int fq = (lane >> 4) * 8;

#define GLL16(g, l) __builtin_amdgcn_global_load_lds( \
    (const __attribute__((address_space(1))) void*)(g), \
    (__attribute__((address_space(3))) void*)(l), 16, 0, 0)

  for (int k0 = kstart; k0 < kend; k0 += 32) {
    GLL16(aG1 + k0, lA1);
    GLL16(aG2 + k0, lA2);
    GLL16(bG1 + k0, lB1);
    GLL16(bG2 + k0, lB2);
    __syncthreads();
    short8 af[4], bfv[4];
#pragma unroll
    for (int mi = 0; mi < 4; ++mi)
      af[mi] = *(const short8*)(As + (wm + mi * 16 + fr) * 32 + fq);
#pragma unroll
    for (int ni = 0; ni < 4; ++ni)
      bfv[ni] = *(const short8*)(Bs + (wn + ni * 16 + fr) * 32 + fq);
#pragma unroll
    for (int mi = 0; mi < 4; ++mi)
#pragma unroll
      for (int ni = 0; ni < 4; ++ni)
        acc[mi][ni] = __builtin_amdgcn_mfma_f32_16x16x32_bf16(af[mi], bfv[ni], acc[mi][ni], 0, 0, 0);
    __syncthreads();
  }
#undef GLL16

  if (OUT_KIND == 0) {
    unsigned short* Ct = (unsigned short*)Cv;
#pragma unroll
    for (int mi = 0; mi < 4; ++mi) {
      const int mbase = m0 + wm + mi * 16 + (lane >> 4) * 4;
      if (mbase < M) {
#pragma unroll
        for (int ni = 0; ni < 4; ++ni) {
          const int n = n0 + wn + ni * 16 + fr;
          ushort4 o;
          o.x = f2bf(acc[mi][ni][0]);
          o.y = f2bf(acc[mi][ni][1]);
          o.z = f2bf(acc[mi][ni][2]);
          o.w = f2bf(acc[mi][ni][3]);
          *(ushort4*)(Ct + (size_t)n * ldc + mbase) = o;
        }
      }
    }
  } else if (OUT_KIND == 3) {
    float* P = (float*)Cv + (size_t)blockIdx.z * (size_t)M * (size_t)N;
#pragma unroll
    for (int ni = 0; ni < 4; ++ni) {
      const int col = n0 + wn + ni * 16 + fr;
#pragma unroll
      for (int mi = 0; mi < 4; ++mi) {
        const int rbase = m0 + wm + mi * 16 + (lane >> 4) * 4;
#pragma unroll
        for (int r = 0; r < 4; ++r) {
          const int row = rbase + r;
          if (row < M) P[(size_t)row * N + col] = acc[mi][ni][r];
        }
      }
    }
  } else {
#pragma unroll
    for (int ni = 0; ni < 4; ++ni) {
      const int col = n0 + wn + ni * 16 + fr;
      const float bv = (EPI >= 1) ? bias[col] : 0.0f;
#pragma unroll
      for (int mi = 0; mi < 4; ++mi) {
        const int rbase = m0 + wm + mi * 16 + (lane >> 4) * 4;
#pragma unroll
        for (int r = 0; r < 4; ++r) {
          const int row = rbase + r;
          if (row < M) {
            float v = acc[mi][ni][r] + bv;
            if (EPI == 2) {
              v = v > 0.f ? v : 0.f;
              const unsigned idx = (unsigned)row * (unsigned)N + (unsigned)col;
              v = dropout_keep(idx) ? v * 2.0f : 0.0f;
            }
            if (OUT_KIND == 2)
              ((float*)Cv)[(size_t)row * ldc + col] = v;
            else
              ((unsigned short*)Cv)[(size_t)row * ldc + col] = f2bf(v);
          }
        }
      }
    }
  }
}

// ---- 256x256 8-wave pipelined split-K GEMM -> f32 partials ----
// grid (N/256, ceil(M/256), S), 512 threads (waves 2M x 4N). BK=64.
// LDS: double-buffered A,B tiles (128 KiB). Staging via global_load_lds with
// pre-swizzled global source (granule ^= row&7) + swizzled ds_read (rule #21).
// Per K-tile: cluster-issue all 8 next-tile loads, WAITV(8) drains exactly the
// current tile's 8 loads; the 8 prefetch loads stay in flight across all 4
// compute phases (~2500cy MFMA >> HBM latency). 5 barriers/tile; setprio
// around each 16-MFMA quadrant (T5 role-split).
__device__ __forceinline__ void bar_sync() {
  asm volatile("" ::: "memory");
  __builtin_amdgcn_s_barrier();
  asm volatile("" ::: "memory");
}
#define WAITV(N) asm volatile("s_waitcnt vmcnt(" #N ")" ::: "memory")

__global__ __launch_bounds__(512, 2) void gemm8p(
    const unsigned short* __restrict__ A, int lda,
    const unsigned short* __restrict__ BT, int ldb,
    float* __restrict__ P,
    int M, int N, int K, int chunk)
{
  __shared__ unsigned short As[2][256 * 64];
  __shared__ unsigned short Bs[2][256 * 64];

  const int tid  = threadIdx.x;
  const int lane = tid & 63;
  const int wave = tid >> 6;
  const int wr = (wave >> 2) * 128;   // 0 / 128
  const int wc = (wave & 3) * 64;     // 0..192
  const int fr  = lane & 15;
  const int fq4 = lane >> 4;          // 0..3

  // bijective XCD swizzle of flattened block id (grid size is a multiple of 8)
  const int gx = gridDim.x, gy = gridDim.y;
  int bid = blockIdx.x + gx * (blockIdx.y + gy * blockIdx.z);
  const int nwg = gx * gy * gridDim.z;
  if ((nwg & 7) == 0) bid = (bid & 7) * (nwg >> 3) + (bid >> 3);
  const int bx = bid % gx;
  const int t1 = bid / gx;
  const int by = t1 % gy;
  const int bz = t1 / gy;

  const int m0 = by * 256;
  const int n0 = bx * 256;
  int kstart = bz * chunk;
  int kend   = kstart + chunk; if (kend > K) kend = K;

  floatx4 acc[8][4];
#pragma unroll
  for (int i = 0; i < 8; ++i)
#pragma unroll
    for (int j = 0; j < 4; ++j) acc[i][j] = (floatx4){0.f, 0.f, 0.f, 0.f};

  // staging: half-tile = 128 rows x 64 k = 16 KB; thread handles rows srow,
  // srow+64(+128,+192); linear LDS dest, swizzled global source granule.
  const int srow = tid >> 3;                       // 0..63
  const int g8   = (tid & 7) * 8;                  // linear dest granule (elems)
  const int gsw  = ((tid & 7) ^ (srow & 7)) * 8;   // swizzled source granule
  const int d00 = (srow      ) * 64 + g8;
  const int d01 = (srow +  64) * 64 + g8;
  const int d10 = (srow + 128) * 64 + g8;
  const int d11 = (srow + 192) * 64 + g8;
  int ra00 = m0 + srow;        if (ra00 > M - 1) ra00 = M - 1;
  int ra01 = m0 + srow +  64;  if (ra01 > M - 1) ra01 = M - 1;
  int ra10 = m0 + srow + 128;  if (ra10 > M - 1) ra10 = M - 1;
  int ra11 = m0 + srow + 192;  if (ra11 > M - 1) ra11 = M - 1;
  const unsigned short* aS00 = A  + (size_t)ra00 * lda + gsw;
  const unsigned short* aS01 = A  + (size_t)ra01 * lda + gsw;
  const unsigned short* aS10 = A  + (size_t)ra10 * lda + gsw;
  const unsigned short* aS11 = A  + (size_t)ra11 * lda + gsw;
  const unsigned short* bS00 = BT + (size_t)(n0 + srow      ) * ldb + gsw;
  const unsigned short* bS01 = BT + (size_t)(n0 + srow +  64) * ldb + gsw;
  const unsigned short* bS10 = BT + (size_t)(n0 + srow + 128) * ldb + gsw;
  const unsigned short* bS11 = BT + (size_t)(n0 + srow + 192) * ldb + gsw;

#define GLL(g, l) __builtin_amdgcn_global_load_lds( \
    (const __attribute__((address_space(1))) void*)(g), \
    (__attribute__((address_space(3))) void*)(l), 16, 0, 0)

// swizzled ds_read: logical (row, k-granule kh*4+fq4) -> granule ^ (row&7);
// row&7 == fr&7 for all frag rows (wr, mh*64, mi2*16, wc, nh*32, ni2*16 all ≡0 mod 8)
#define RDA_HALF(mh) do { \
  _Pragma("unroll") for (int mi2 = 0; mi2 < 4; ++mi2) \
  _Pragma("unroll") for (int kh = 0; kh < 2; ++kh) \
    af[mi2][kh] = *(const short8*)(curA + (wr + (mh)*64 + mi2*16 + fr) * 64 \
                                        + (((kh*4 + fq4) ^ (fr & 7)) * 8)); \
} while (0)
#define RDB_HALF(nh) do { \
  _Pragma("unroll") for (int ni2 = 0; ni2 < 2; ++ni2) \
  _Pragma("unroll") for (int kh = 0; kh < 2; ++kh) \
    bf[(nh)*2 + ni2][kh] = *(const short8*)(curB + (wc + (nh)*32 + ni2*16 + fr) * 64 \
                                                 + (((kh*4 + fq4) ^ (fr & 7)) * 8)); \
} while (0)
#define MFMAQ(mh, nh) do { \
  __builtin_amdgcn_s_setprio(1); \
  _Pragma("unroll") for (int mi2 = 0; mi2 < 4; ++mi2) \
  _Pragma("unroll") for (int ni2 = 0; ni2 < 2; ++ni2) \
  _Pragma("unroll") for (int kh = 0; kh < 2; ++kh) \
    acc[(mh)*4 + mi2][(nh)*2 + ni2] = __builtin_amdgcn_mfma_f32_16x16x32_bf16( \
        af[mi2][kh], bf[(nh)*2 + ni2][kh], acc[(mh)*4 + mi2][(nh)*2 + ni2], 0, 0, 0); \
  __builtin_amdgcn_s_setprio(0); \
} while (0)

  if (kstart < kend) {
    // prologue: prime tile kstart into buffer 0
    GLL(aS00 + kstart, As[0] + d00);
    GLL(aS01 + kstart, As[0] + d01);
    GLL(aS10 + kstart, As[0] + d10);
    GLL(aS11 + kstart, As[0] + d11);
    GLL(bS00 + kstart, Bs[0] + d00);
    GLL(bS01 + kstart, Bs[0] + d01);
    GLL(bS10 + kstart, Bs[0] + d10);
    GLL(bS11 + kstart, Bs[0] + d11);

    int cur = 0;
    for (int kt = kstart; kt < kend; kt += 64, cur ^= 1) {
      const unsigned short* curA = As[cur];
      const unsigned short* curB = Bs[cur];
      unsigned short* nxA = As[cur ^ 1];
      unsigned short* nxB = Bs[cur ^ 1];
      const int kn = kt + 64;
      short8 af[4][2];
      short8 bf[4][2];

      // cluster-issue next tile's 8 loads; WAITV(8) == exactly current tile done,
      // prefetch stays in flight across all compute phases (counted vmcnt, T4).
      if (kn < kend) {
        GLL(aS00 + kn, nxA + d00); GLL(aS01 + kn, nxA + d01);
        GLL(aS10 + kn, nxA + d10); GLL(aS11 + kn, nxA + d11);
        GLL(bS00 + kn, nxB + d00); GLL(bS01 + kn, nxB + d01);
        GLL(bS10 + kn, nxB + d10); GLL(bS11 + kn, nxB + d11);
        WAITV(8);
      } else {
        WAITV(0);
      }
      bar_sync();          // all waves' current-tile loads are in LDS

      // phase 0: quad (m0,n0)
      RDA_HALF(0);
      RDB_HALF(0);
      MFMAQ(0, 0);
      bar_sync();

      // phase 1: quad (m0,n1)  (af(mh0) reused)
      RDB_HALF(1);
      MFMAQ(0, 1);
      bar_sync();

      // phase 2: quad (m1,n0)  (bf(nh0) reused)
      RDA_HALF(1);
      MFMAQ(1, 0);
      bar_sync();

      // phase 3: quad (m1,n1)  (af(mh1), bf(nh1) reused)
      MFMAQ(1, 1);
      bar_sync();          // reads of this buffer done before next iter's issues
    }
  }
#undef GLL
#undef RDA_HALF
#undef RDB_HALF
#undef MFMAQ

  // store f32 partials: C/D layout col=lane&15, row=(lane>>4)*4+reg
  float* Pz = P + (size_t)bz * ((size_t)M * (size_t)N);
#pragma unroll
  for (int mi = 0; mi < 8; ++mi) {
    const int rb = m0 + wr + mi * 16 + fq4 * 4;
#pragma unroll
    for (int r = 0; r < 4; ++r) {
      const int row = rb + r;
      if (row < M) {
        float* pr = Pz + (size_t)row * N + n0 + wc + fr;
#pragma unroll
        for (int nj = 0; nj < 4; ++nj)
          pr[nj * 16] = acc[mi][nj][r];
      }
    }
  }
}

// ---- split-K reduce + epilogue ----
// EPI: 2 = bias+relu+dropout -> bf16; 1 = bias -> bf16; 3 = bias -> f32
template<int EPI>
__global__ void reduce_epi_kernel(const float* __restrict__ P, void* __restrict__ outv,
                                  const float* __restrict__ bias,
                                  int S, int total4, unsigned nmask, size_t MN) {
  const int t = blockIdx.x * blockDim.x + threadIdx.x;
  if (t >= total4) return;
  const size_t off = (size_t)t * 4;
  float4 a = *(const float4*)(P + off);
  for (int s = 1; s < S; ++s) {
    const float4 b = *(const float4*)(P + (size_t)s * MN + off);
    a.x += b.x; a.y += b.y; a.z += b.z; a.w += b.w;
  }
  const unsigned col = (unsigned)off & nmask;   // N power of 2; off%4==0
  a.x += bias[col]; a.y += bias[col + 1]; a.z += bias[col + 2]; a.w += bias[col + 3];
  if (EPI == 2) {
    float* e = &a.x;
#pragma unroll
    for (int j = 0; j < 4; ++j) {
      float v = e[j] > 0.f ? e[j] : 0.f;
      e[j] = dropout_keep((unsigned)off + j) ? v * 2.0f : 0.0f;
    }
  }
  if (EPI == 3) {
    *(float4*)((float*)outv + off) = a;
  } else {
    ushort4 o;
    o.x = f2bf(a.x); o.y = f2bf(a.y); o.z = f2bf(a.z); o.w = f2bf(a.w);
    *(ushort4*)((unsigned short*)outv + off) = o;
  }
}

static inline int pick_split(size_t avail, size_t per_split, int target) {
  int s = 1;
  while (s < target && (size_t)(s * 2) * per_split <= avail) s *= 2;
  return s;
}

extern "C" void kernel_launch(void* const* d_in, const int* in_sizes, int n_in,
                              void* d_out, int out_size, void* d_ws, size_t ws_size,
                              hipStream_t stream) {
  const float* x   = (const float*)d_in[0];
  const float* adj = (const float*)d_in[1];
  const float* W1  = (const float*)d_in[2];
  const float* b1  = (const float*)d_in[3];
  const float* W2  = (const float*)d_in[4];
  const float* b2  = (const float*)d_in[5];
  const float* W3  = (const float*)d_in[6];
  const float* b3  = (const float*)d_in[7];
  float* out = (float*)d_out;

  char* ws = (char*)d_ws;
  unsigned short* adjb = (unsigned short*)(ws);                  // 10000 x 10048 bf16
  unsigned short* xb   = (unsigned short*)(ws + 200960000ull);   // 10000 x 1024
  unsigned short* w1t  = (unsigned short*)(ws + 221440000ull);   // 512 x 1024 (W1^T)
  unsigned short* w2t  = (unsigned short*)(ws + 222488576ull);   // 256 x 512
  unsigned short* w3t  = (unsigned short*)(ws + 222750720ull);   // 128 x 256
  unsigned short* h1t  = (unsigned short*)(ws + 222816256ull);   // 512 x 10048 (H1^T)
  unsigned short* x1   = (unsigned short*)(ws + 233105408ull);   // 10000 x 512
  unsigned short* h2t  = (unsigned short*)(ws + 243345408ull);   // 256 x 10048
  unsigned short* x2   = (unsigned short*)(ws + 248489984ull);   // 10000 x 256
  unsigned short* h3t  = (unsigned short*)(ws + 253609984ull);   // 128 x 10048
  float*          P    = (float*)(ws + 256182272ull);            // split-K partials
  const size_t avail = (ws_size > 256182272ull) ? ws_size - 256182272ull : 0;

  cast_adj_kernel<<<dim3(10, 10000), 256, 0, stream>>>(adj, adjb);
  cast_vec_kernel<<<10000, 256, 0, stream>>>(x, xb, 2560000);
  castT_kernel<<<2048, 256, 0, stream>>>(W1, w1t, 1024, 512);
  castT_kernel<<<512, 256, 0, stream>>>(W2, w2t, 512, 256);
  castT_kernel<<<128, 256, 0, stream>>>(W3, w3t, 256, 128);
  zero_pad_kernel<<<96, 256, 0, stream>>>(h1t, 512);
  zero_pad_kernel<<<48, 256, 0, stream>>>(h2t, 256);
  zero_pad_kernel<<<24, 256, 0, stream>>>(h3t, 128);

  // H1^T = (x @ W1)^T
  gemm_mfma<0, 0><<<dim3(4, 79), 256, 0, stream>>>(xb, 1024, w1t, 1024, h1t, KPAD, nullptr, MROWS, 512, 1024, 1024);

  // x1 = dropout(relu(adj @ H1 + b1))
  if (avail >= 20480000ull) {
    const int S1 = pick_split(avail, 20480000ull, 8);
    const int chunk = ((157 + S1 - 1) / S1) * 64;
    gemm8p<<<dim3(2, 40, S1), 512, 0, stream>>>(adjb, KPAD, h1t, KPAD, P, MROWS, 512, KPAD, chunk);
    reduce_epi_kernel<2><<<5000, 256, 0, stream>>>(P, x1, b1, S1, 1280000, 511u, 5120000ull);
  } else {
    gemm_mfma<1, 2><<<dim3(4, 79), 256, 0, stream>>>(adjb, KPAD, h1t, KPAD, x1, 512, b1, MROWS, 512, KPAD, KPAD);
  }

  // H2^T = (x1 @ W2)^T
  gemm_mfma<0, 0><<<dim3(2, 79), 256, 0, stream>>>(x1, 512, w2t, 512, h2t, KPAD, nullptr, MROWS, 256, 512, 512);

  // x2 = adj @ H2 + b2
  if (avail >= 10240000ull) {
    const int S2 = pick_split(avail, 10240000ull, 16);
    const int chunk = ((157 + S2 - 1) / S2) * 64;
    gemm8p<<<dim3(1, 40, S2), 512, 0, stream>>>(adjb, KPAD, h2t, KPAD, P, MROWS, 256, KPAD, chunk);
    reduce_epi_kernel<1><<<2500, 256, 0, stream>>>(P, x2, b2, S2, 640000, 255u, 2560000ull);
  } else {
    gemm_mfma<1, 1><<<dim3(2, 79), 256, 0, stream>>>(adjb, KPAD, h2t, KPAD, x2, 256, b2, MROWS, 256, KPAD, KPAD);
  }

  // H3^T = (x2 @ W3)^T
  gemm_mfma<0, 0><<<dim3(1, 79), 256, 0, stream>>>(x2, 256, w3t, 256, h3t, KPAD, nullptr, MROWS, 128, 256, 256);

  // out = adj @ H3 + b3  (f32)
  if (avail >= 5120000ull) {
    const int S3 = pick_split(avail, 5120000ull, 16);
    const int chunk = ((314 + S3 - 1) / S3) * 32;
    gemm_mfma<3, 0><<<dim3(1, 79, S3), 256, 0, stream>>>(adjb, KPAD, h3t, KPAD, P, 128, nullptr, MROWS, 128, KPAD, chunk);
    reduce_epi_kernel<3><<<1250, 256, 0, stream>>>(P, out, b3, S3, 320000, 127u, 1280000ull);
  } else {
    gemm_mfma<2, 1><<<dim3(1, 79), 256, 0, stream>>>(adjb, KPAD, h3t, KPAD, out, 128, b3, MROWS, 128, KPAD, KPAD);
  }
}

// Round 3
// 1008.505 us; speedup vs baseline: 1.0552x; 1.0552x over previous
//
#include <hip/hip_runtime.h>
#include <hip/hip_bf16.h>
#include <stdint.h>

// GCN1: x3 = adj@(x2@W3)+b3; x2 = adj@(x1@W2)+b2; x1 = drop(relu(adj@(x@W1)+b1))
// bf16 MFMA GEMMs (2% rel tolerance), exact JAX threefry dropout.
// R2: split-K for the three adj GEMMs.
// R3: 256x256 8-wave pipelined GEMM for the two big adj GEMMs.
// R4: clustered 8-load prefetch + single WAITV(8) per K-tile (correct counted-vmcnt).
// R5: bf16 split-K partials (halves 820 MB of partial write+read streaming;
//     +~0.4% quadrature error, well under 2% tol) + 8-wide vectorized reduce.

#define MROWS 10000
#define KPAD  10048   // 10000 padded to multiple of 64 (157 BK=64 tiles)

typedef __attribute__((ext_vector_type(8))) short short8;
typedef __attribute__((ext_vector_type(4))) float floatx4;

__device__ __forceinline__ unsigned short f2bf(float f) {
  union { float f; unsigned u; } v; v.f = f;
  unsigned u = v.u;
  u += 0x7fffu + ((u >> 16) & 1u);   // round-to-nearest-even
  return (unsigned short)(u >> 16);
}

__device__ __forceinline__ float bf2f(unsigned short u) {
  union { unsigned u; float f; } v; v.u = (unsigned)u << 16;
  return v.f;
}

// ---- exact JAX threefry2x32-20, key(42) = (0, 42), iota split in halves ----
__device__ __forceinline__ bool dropout_keep(unsigned i) {
  const unsigned halfn = 2560000u;           // (10000*512)/2
  const unsigned j = (i < halfn) ? i : (i - halfn);
  unsigned x0 = j, x1 = j + halfn;
  const unsigned k0 = 0u, k1 = 42u, k2 = 0u ^ 42u ^ 0x1BD11BDAu;
  x0 += k0; x1 += k1;
#define TFR(r) { x0 += x1; x1 = (x1 << (r)) | (x1 >> (32 - (r))); x1 ^= x0; }
  TFR(13) TFR(15) TFR(26) TFR(6)   x0 += k1; x1 += k2 + 1u;
  TFR(17) TFR(29) TFR(16) TFR(24)  x0 += k2; x1 += k0 + 2u;
  TFR(13) TFR(15) TFR(26) TFR(6)   x0 += k0; x1 += k1 + 3u;
  TFR(17) TFR(29) TFR(16) TFR(24)  x0 += k1; x1 += k2 + 4u;
  TFR(13) TFR(15) TFR(26) TFR(6)   x0 += k2; x1 += k0 + 5u;
#undef TFR
  const unsigned bits = (i < halfn) ? x0 : x1;
  return bits < 0x80000000u;   // uniform(bits) < 0.5, exact transform
}

// ---- cast kernels ----
__global__ void cast_adj_kernel(const float* __restrict__ in, unsigned short* __restrict__ out) {
  const int q = blockIdx.x * blockDim.x + threadIdx.x;  // quad of 4 cols
  const int row = blockIdx.y;
  if (q >= 2512) return;                                 // 10048/4
  const int col = q * 4;
  ushort4 o;
  if (col < 10000) {
    const float4 v = *(const float4*)(in + (size_t)row * 10000 + col);
    o.x = f2bf(v.x); o.y = f2bf(v.y); o.z = f2bf(v.z); o.w = f2bf(v.w);
  } else {
    o.x = 0; o.y = 0; o.z = 0; o.w = 0;                  // K-pad zeros
  }
  *(ushort4*)(out + (size_t)row * KPAD + col) = o;
}

__global__ void cast_vec_kernel(const float* __restrict__ in, unsigned short* __restrict__ out, int n4) {
  const int id = blockIdx.x * blockDim.x + threadIdx.x;
  if (id >= n4) return;
  const float4 v = ((const float4*)in)[id];
  ushort4 o; o.x = f2bf(v.x); o.y = f2bf(v.y); o.z = f2bf(v.z); o.w = f2bf(v.w);
  ((ushort4*)out)[id] = o;
}

// W (K x N) f32 -> W^T (N x K) bf16
__global__ void castT_kernel(const float* __restrict__ in, unsigned short* __restrict__ out, int K, int N) {
  const int id = blockIdx.x * blockDim.x + threadIdx.x;
  if (id >= K * N) return;
  const int n = id / K, k = id % K;
  out[(size_t)n * K + k] = f2bf(in[(size_t)k * N + n]);
}

// zero pad cols 10000..10048 of an (rows x KPAD) buffer
__global__ void zero_pad_kernel(unsigned short* __restrict__ p, int rows) {
  const int id = blockIdx.x * blockDim.x + threadIdx.x;
  if (id >= rows * 48) return;
  const int r = id / 48, c = id % 48;
  p[(size_t)r * KPAD + 10000 + c] = 0;
}

// ---- bf16 MFMA GEMM (legacy 128x128): C = A(MxK) @ BT'(KxN) ----
// OUT_KIND: 0 = bf16 transposed store (C^T, ldc = row stride of C^T)
//           1 = bf16 row-major, 2 = f32 row-major,
//           3 = bf16 partial (split-K): P[z*M*N + row*N + col] = bf16(acc)  (no bias)
// EPI: 0 none, 1 +bias, 2 +bias,relu,dropout(x2)
template<int OUT_KIND, int EPI>
__global__ __launch_bounds__(256, 2) void gemm_mfma(
    const unsigned short* __restrict__ A, int lda,
    const unsigned short* __restrict__ BT, int ldb,
    void* __restrict__ Cv, int ldc,
    const float* __restrict__ bias,
    int M, int N, int K,
    int chunk)
{
  __shared__ unsigned short As[128 * 32];
  __shared__ unsigned short Bs[128 * 32];

  const int tid  = threadIdx.x;
  const int lane = tid & 63;
  const int wave = tid >> 6;
  const int m0 = blockIdx.y * 128;
  const int n0 = blockIdx.x * 128;
  const int wm = (wave & 1) * 64;
  const int wn = (wave >> 1) * 64;

  int kstart = 0, kend = K;
  if (OUT_KIND == 3) {
    kstart = blockIdx.z * chunk;
    kend   = kstart + chunk; if (kend > K) kend = K;
  }

  floatx4 acc[4][4];
#pragma unroll
  for (int i = 0; i < 4; ++i)
#pragma unroll
    for (int j = 0; j < 4; ++j) acc[i][j] = (floatx4){0.f, 0.f, 0.f, 0.f};

  const int c1 = tid, c2 = tid + 256;
  int ar1 = m0 + (c1 >> 2); if (ar1 > M - 1) ar1 = M - 1;
  int ar2 = m0 + (c2 >> 2); if (ar2 > M - 1) ar2 = M - 1;
  const int br1 = n0 + (c1 >> 2);
  const int br2 = n0 + (c2 >> 2);
  const unsigned short* aG1 = A  + (size_t)ar1 * lda + (c1 & 3) * 8;
  const unsigned short* aG2 = A  + (size_t)ar2 * lda + (c2 & 3) * 8;
  const unsigned short* bG1 = BT + (size_t)br1 * ldb + (c1 & 3) * 8;
  const unsigned short* bG2 = BT + (size_t)br2 * ldb + (c2 & 3) * 8;
  unsigned short* lA1 = As + c1 * 8;
  unsigned short* lA2 = As + c2 * 8;
  unsigned short* lB1 = Bs + c1 * 8;
  unsigned short* lB2 = Bs + c2 * 8;

  const int fr = lane & 15;
  const int fq = (lane >> 4) * 8;

#define GLL16(g, l) __builtin_amdgcn_global_load_lds( \
    (const __attribute__((address_space(1))) void*)(g), \
    (__attribute__((address_space(3))) void*)(l), 16, 0, 0)

  for (int k0 = kstart; k0 < kend; k0 += 32) {
    GLL16(aG1 + k0, lA1);
    GLL16(aG2 + k0, lA2);
    GLL16(bG1 + k0, lB1);
    GLL16(bG2 + k0, lB2);
    __syncthreads();
    short8 af[4], bfv[4];
#pragma unroll
    for (int mi = 0; mi < 4; ++mi)
      af[mi] = *(const short8*)(As + (wm + mi * 16 + fr) * 32 + fq);
#pragma unroll
    for (int ni = 0; ni < 4; ++ni)
      bfv[ni] = *(const short8*)(Bs + (wn + ni * 16 + fr) * 32 + fq);
#pragma unroll
    for (int mi = 0; mi < 4; ++mi)
#pragma unroll
      for (int ni = 0; ni < 4; ++ni)
        acc[mi][ni] = __builtin_amdgcn_mfma_f32_16x16x32_bf16(af[mi], bfv[ni], acc[mi][ni], 0, 0, 0);
    __syncthreads();
  }
#undef GLL16

  if (OUT_KIND == 0) {
    unsigned short* Ct = (unsigned short*)Cv;
#pragma unroll
    for (int mi = 0; mi < 4; ++mi) {
      const int mbase = m0 + wm + mi * 16 + (lane >> 4) * 4;
      if (mbase < M) {
#pragma unroll
        for (int ni = 0; ni < 4; ++ni) {
          const int n = n0 + wn + ni * 16 + fr;
          ushort4 o;
          o.x = f2bf(acc[mi][ni][0]);
          o.y = f2bf(acc[mi][ni][1]);
          o.z = f2bf(acc[mi][ni][2]);
          o.w = f2bf(acc[mi][ni][3]);
          *(ushort4*)(Ct + (size_t)n * ldc + mbase) = o;
        }
      }
    }
  } else if (OUT_KIND == 3) {
    unsigned short* Pp = (unsigned short*)Cv + (size_t)blockIdx.z * (size_t)M * (size_t)N;
#pragma unroll
    for (int ni = 0; ni < 4; ++ni) {
      const int col = n0 + wn + ni * 16 + fr;
#pragma unroll
      for (int mi = 0; mi < 4; ++mi) {
        const int rbase = m0 + wm + mi * 16 + (lane >> 4) * 4;
#pragma unroll
        for (int r = 0; r < 4; ++r) {
          const int row = rbase + r;
          if (row < M) Pp[(size_t)row * N + col] = f2bf(acc[mi][ni][r]);
        }
      }
    }
  } else {
#pragma unroll
    for (int ni = 0; ni < 4; ++ni) {
      const int col = n0 + wn + ni * 16 + fr;
      const float bv = (EPI >= 1) ? bias[col] : 0.0f;
#pragma unroll
      for (int mi = 0; mi < 4; ++mi) {
        const int rbase = m0 + wm + mi * 16 + (lane >> 4) * 4;
#pragma unroll
        for (int r = 0; r < 4; ++r) {
          const int row = rbase + r;
          if (row < M) {
            float v = acc[mi][ni][r] + bv;
            if (EPI == 2) {
              v = v > 0.f ? v : 0.f;
              const unsigned idx = (unsigned)row * (unsigned)N + (unsigned)col;
              v = dropout_keep(idx) ? v * 2.0f : 0.0f;
            }
            if (OUT_KIND == 2)
              ((float*)Cv)[(size_t)row * ldc + col] = v;
            else
              ((unsigned short*)Cv)[(size_t)row * ldc + col] = f2bf(v);
          }
        }
      }
    }
  }
}

// ---- 256x256 8-wave pipelined split-K GEMM -> bf16 partials ----
// grid (N/256, ceil(M/256), S), 512 threads (waves 2M x 4N). BK=64.
// LDS: double-buffered A,B tiles (128 KiB). Staging via global_load_lds with
// pre-swizzled global source (granule ^= row&7) + swizzled ds_read (rule #21).
// Per K-tile: cluster-issue all 8 next-tile loads, WAITV(8) drains exactly the
// current tile's 8 loads; the 8 prefetch loads stay in flight across all 4
// compute phases. 5 barriers/tile; setprio around each 16-MFMA quadrant (T5).
__device__ __forceinline__ void bar_sync() {
  asm volatile("" ::: "memory");
  __builtin_amdgcn_s_barrier();
  asm volatile("" ::: "memory");
}
#define WAITV(N) asm volatile("s_waitcnt vmcnt(" #N ")" ::: "memory")

__global__ __launch_bounds__(512, 2) void gemm8p(
    const unsigned short* __restrict__ A, int lda,
    const unsigned short* __restrict__ BT, int ldb,
    unsigned short* __restrict__ P,
    int M, int N, int K, int chunk)
{
  __shared__ unsigned short As[2][256 * 64];
  __shared__ unsigned short Bs[2][256 * 64];

  const int tid  = threadIdx.x;
  const int lane = tid & 63;
  const int wave = tid >> 6;
  const int wr = (wave >> 2) * 128;   // 0 / 128
  const int wc = (wave & 3) * 64;     // 0..192
  const int fr  = lane & 15;
  const int fq4 = lane >> 4;          // 0..3

  // bijective XCD swizzle of flattened block id (grid size is a multiple of 8)
  const int gx = gridDim.x, gy = gridDim.y;
  int bid = blockIdx.x + gx * (blockIdx.y + gy * blockIdx.z);
  const int nwg = gx * gy * gridDim.z;
  if ((nwg & 7) == 0) bid = (bid & 7) * (nwg >> 3) + (bid >> 3);
  const int bx = bid % gx;
  const int t1 = bid / gx;
  const int by = t1 % gy;
  const int bz = t1 / gy;

  const int m0 = by * 256;
  const int n0 = bx * 256;
  int kstart = bz * chunk;
  int kend   = kstart + chunk; if (kend > K) kend = K;

  floatx4 acc[8][4];
#pragma unroll
  for (int i = 0; i < 8; ++i)
#pragma unroll
    for (int j = 0; j < 4; ++j) acc[i][j] = (floatx4){0.f, 0.f, 0.f, 0.f};

  // staging: half-tile = 128 rows x 64 k = 16 KB; thread handles rows srow,
  // srow+64(+128,+192); linear LDS dest, swizzled global source granule.
  const int srow = tid >> 3;                       // 0..63
  const int g8   = (tid & 7) * 8;                  // linear dest granule (elems)
  const int gsw  = ((tid & 7) ^ (srow & 7)) * 8;   // swizzled source granule
  const int d00 = (srow      ) * 64 + g8;
  const int d01 = (srow +  64) * 64 + g8;
  const int d10 = (srow + 128) * 64 + g8;
  const int d11 = (srow + 192) * 64 + g8;
  int ra00 = m0 + srow;        if (ra00 > M - 1) ra00 = M - 1;
  int ra01 = m0 + srow +  64;  if (ra01 > M - 1) ra01 = M - 1;
  int ra10 = m0 + srow + 128;  if (ra10 > M - 1) ra10 = M - 1;
  int ra11 = m0 + srow + 192;  if (ra11 > M - 1) ra11 = M - 1;
  const unsigned short* aS00 = A  + (size_t)ra00 * lda + gsw;
  const unsigned short* aS01 = A  + (size_t)ra01 * lda + gsw;
  const unsigned short* aS10 = A  + (size_t)ra10 * lda + gsw;
  const unsigned short* aS11 = A  + (size_t)ra11 * lda + gsw;
  const unsigned short* bS00 = BT + (size_t)(n0 + srow      ) * ldb + gsw;
  const unsigned short* bS01 = BT + (size_t)(n0 + srow +  64) * ldb + gsw;
  const unsigned short* bS10 = BT + (size_t)(n0 + srow + 128) * ldb + gsw;
  const unsigned short* bS11 = BT + (size_t)(n0 + srow + 192) * ldb + gsw;

#define GLL(g, l) __builtin_amdgcn_global_load_lds( \
    (const __attribute__((address_space(1))) void*)(g), \
    (__attribute__((address_space(3))) void*)(l), 16, 0, 0)

// swizzled ds_read: logical (row, k-granule kh*4+fq4) -> granule ^ (row&7);
// row&7 == fr&7 for all frag rows (wr, mh*64, mi2*16, wc, nh*32, ni2*16 all ≡0 mod 8)
#define RDA_HALF(mh) do { \
  _Pragma("unroll") for (int mi2 = 0; mi2 < 4; ++mi2) \
  _Pragma("unroll") for (int kh = 0; kh < 2; ++kh) \
    af[mi2][kh] = *(const short8*)(curA + (wr + (mh)*64 + mi2*16 + fr) * 64 \
                                        + (((kh*4 + fq4) ^ (fr & 7)) * 8)); \
} while (0)
#define RDB_HALF(nh) do { \
  _Pragma("unroll") for (int ni2 = 0; ni2 < 2; ++ni2) \
  _Pragma("unroll") for (int kh = 0; kh < 2; ++kh) \
    bf[(nh)*2 + ni2][kh] = *(const short8*)(curB + (wc + (nh)*32 + ni2*16 + fr) * 64 \
                                                 + (((kh*4 + fq4) ^ (fr & 7)) * 8)); \
} while (0)
#define MFMAQ(mh, nh) do { \
  __builtin_amdgcn_s_setprio(1); \
  _Pragma("unroll") for (int mi2 = 0; mi2 < 4; ++mi2) \
  _Pragma("unroll") for (int ni2 = 0; ni2 < 2; ++ni2) \
  _Pragma("unroll") for (int kh = 0; kh < 2; ++kh) \
    acc[(mh)*4 + mi2][(nh)*2 + ni2] = __builtin_amdgcn_mfma_f32_16x16x32_bf16( \
        af[mi2][kh], bf[(nh)*2 + ni2][kh], acc[(mh)*4 + mi2][(nh)*2 + ni2], 0, 0, 0); \
  __builtin_amdgcn_s_setprio(0); \
} while (0)

  if (kstart < kend) {
    // prologue: prime tile kstart into buffer 0
    GLL(aS00 + kstart, As[0] + d00);
    GLL(aS01 + kstart, As[0] + d01);
    GLL(aS10 + kstart, As[0] + d10);
    GLL(aS11 + kstart, As[0] + d11);
    GLL(bS00 + kstart, Bs[0] + d00);
    GLL(bS01 + kstart, Bs[0] + d01);
    GLL(bS10 + kstart, Bs[0] + d10);
    GLL(bS11 + kstart, Bs[0] + d11);

    int cur = 0;
    for (int kt = kstart; kt < kend; kt += 64, cur ^= 1) {
      const unsigned short* curA = As[cur];
      const unsigned short* curB = Bs[cur];
      unsigned short* nxA = As[cur ^ 1];
      unsigned short* nxB = Bs[cur ^ 1];
      const int kn = kt + 64;
      short8 af[4][2];
      short8 bf[4][2];

      // cluster-issue next tile's 8 loads; WAITV(8) == exactly current tile done,
      // prefetch stays in flight across all compute phases (counted vmcnt, T4).
      if (kn < kend) {
        GLL(aS00 + kn, nxA + d00); GLL(aS01 + kn, nxA + d01);
        GLL(aS10 + kn, nxA + d10); GLL(aS11 + kn, nxA + d11);
        GLL(bS00 + kn, nxB + d00); GLL(bS01 + kn, nxB + d01);
        GLL(bS10 + kn, nxB + d10); GLL(bS11 + kn, nxB + d11);
        WAITV(8);
      } else {
        WAITV(0);
      }
      bar_sync();          // all waves' current-tile loads are in LDS

      // phase 0: quad (m0,n0)
      RDA_HALF(0);
      RDB_HALF(0);
      MFMAQ(0, 0);
      bar_sync();

      // phase 1: quad (m0,n1)  (af(mh0) reused)
      RDB_HALF(1);
      MFMAQ(0, 1);
      bar_sync();

      // phase 2: quad (m1,n0)  (bf(nh0) reused)
      RDA_HALF(1);
      MFMAQ(1, 0);
      bar_sync();

      // phase 3: quad (m1,n1)  (af(mh1), bf(nh1) reused)
      MFMAQ(1, 1);
      bar_sync();          // reads of this buffer done before next iter's issues
    }
  }
#undef GLL
#undef RDA_HALF
#undef RDB_HALF
#undef MFMAQ

  // store bf16 partials: C/D layout col=lane&15, row=(lane>>4)*4+reg
  unsigned short* Pz = P + (size_t)bz * ((size_t)M * (size_t)N);
#pragma unroll
  for (int mi = 0; mi < 8; ++mi) {
    const int rb = m0 + wr + mi * 16 + fq4 * 4;
#pragma unroll
    for (int r = 0; r < 4; ++r) {
      const int row = rb + r;
      if (row < M) {
        unsigned short* pr = Pz + (size_t)row * N + n0 + wc + fr;
#pragma unroll
        for (int nj = 0; nj < 4; ++nj)
          pr[nj * 16] = f2bf(acc[mi][nj][r]);
      }
    }
  }
}

// ---- split-K reduce + epilogue (bf16 partials, f32 accumulate) ----
// EPI: 2 = bias+relu+dropout -> bf16; 1 = bias -> bf16; 3 = bias -> f32
template<int EPI>
__global__ void reduce_epi_kernel(const unsigned short* __restrict__ P, void* __restrict__ outv,
                                  const float* __restrict__ bias,
                                  int S, int total8, unsigned nmask, size_t MN) {
  const int t = blockIdx.x * blockDim.x + threadIdx.x;
  if (t >= total8) return;
  const size_t off = (size_t)t * 8;
  float a[8];
  {
    const short8 v = *(const short8*)(P + off);
#pragma unroll
    for (int j = 0; j < 8; ++j) a[j] = bf2f((unsigned short)v[j]);
  }
  for (int s = 1; s < S; ++s) {
    const short8 v = *(const short8*)(P + (size_t)s * MN + off);
#pragma unroll
    for (int j = 0; j < 8; ++j) a[j] += bf2f((unsigned short)v[j]);
  }
  const unsigned col = (unsigned)off & nmask;   // N power of 2 >= 128; off%8==0
#pragma unroll
  for (int j = 0; j < 8; ++j) a[j] += bias[col + j];
  if (EPI == 2) {
#pragma unroll
    for (int j = 0; j < 8; ++j) {
      float v = a[j] > 0.f ? a[j] : 0.f;
      a[j] = dropout_keep((unsigned)off + j) ? v * 2.0f : 0.0f;
    }
  }
  if (EPI == 3) {
    float4 o1 = {a[0], a[1], a[2], a[3]};
    float4 o2 = {a[4], a[5], a[6], a[7]};
    *(float4*)((float*)outv + off) = o1;
    *(float4*)((float*)outv + off + 4) = o2;
  } else {
    short8 o;
#pragma unroll
    for (int j = 0; j < 8; ++j) o[j] = (short)f2bf(a[j]);
    *(short8*)((unsigned short*)outv + off) = o;
  }
}

static inline int pick_split(size_t avail, size_t per_split, int target) {
  int s = 1;
  while (s < target && (size_t)(s * 2) * per_split <= avail) s *= 2;
  return s;
}

extern "C" void kernel_launch(void* const* d_in, const int* in_sizes, int n_in,
                              void* d_out, int out_size, void* d_ws, size_t ws_size,
                              hipStream_t stream) {
  const float* x   = (const float*)d_in[0];
  const float* adj = (const float*)d_in[1];
  const float* W1  = (const float*)d_in[2];
  const float* b1  = (const float*)d_in[3];
  const float* W2  = (const float*)d_in[4];
  const float* b2  = (const float*)d_in[5];
  const float* W3  = (const float*)d_in[6];
  const float* b3  = (const float*)d_in[7];
  float* out = (float*)d_out;

  char* ws = (char*)d_ws;
  unsigned short* adjb = (unsigned short*)(ws);                  // 10000 x 10048 bf16
  unsigned short* xb   = (unsigned short*)(ws + 200960000ull);   // 10000 x 1024
  unsigned short* w1t  = (unsigned short*)(ws + 221440000ull);   // 512 x 1024 (W1^T)
  unsigned short* w2t  = (unsigned short*)(ws + 222488576ull);   // 256 x 512
  unsigned short* w3t  = (unsigned short*)(ws + 222750720ull);   // 128 x 256
  unsigned short* h1t  = (unsigned short*)(ws + 222816256ull);   // 512 x 10048 (H1^T)
  unsigned short* x1   = (unsigned short*)(ws + 233105408ull);   // 10000 x 512
  unsigned short* h2t  = (unsigned short*)(ws + 243345408ull);   // 256 x 10048
  unsigned short* x2   = (unsigned short*)(ws + 248489984ull);   // 10000 x 256
  unsigned short* h3t  = (unsigned short*)(ws + 253609984ull);   // 128 x 10048
  unsigned short* Pb   = (unsigned short*)(ws + 256182272ull);   // bf16 split-K partials
  const size_t avail = (ws_size > 256182272ull) ? ws_size - 256182272ull : 0;

  cast_adj_kernel<<<dim3(10, 10000), 256, 0, stream>>>(adj, adjb);
  cast_vec_kernel<<<10000, 256, 0, stream>>>(x, xb, 2560000);
  castT_kernel<<<2048, 256, 0, stream>>>(W1, w1t, 1024, 512);
  castT_kernel<<<512, 256, 0, stream>>>(W2, w2t, 512, 256);
  castT_kernel<<<128, 256, 0, stream>>>(W3, w3t, 256, 128);
  zero_pad_kernel<<<96, 256, 0, stream>>>(h1t, 512);
  zero_pad_kernel<<<48, 256, 0, stream>>>(h2t, 256);
  zero_pad_kernel<<<24, 256, 0, stream>>>(h3t, 128);

  // H1^T = (x @ W1)^T
  gemm_mfma<0, 0><<<dim3(4, 79), 256, 0, stream>>>(xb, 1024, w1t, 1024, h1t, KPAD, nullptr, MROWS, 512, 1024, 1024);

  // x1 = dropout(relu(adj @ H1 + b1))
  if (avail >= 10240000ull) {
    const int S1 = pick_split(avail, 10240000ull, 8);       // 10000x512 bf16/split
    const int chunk = ((157 + S1 - 1) / S1) * 64;
    gemm8p<<<dim3(2, 40, S1), 512, 0, stream>>>(adjb, KPAD, h1t, KPAD, Pb, MROWS, 512, KPAD, chunk);
    reduce_epi_kernel<2><<<2500, 256, 0, stream>>>(Pb, x1, b1, S1, 640000, 511u, 5120000ull);
  } else {
    gemm_mfma<1, 2><<<dim3(4, 79), 256, 0, stream>>>(adjb, KPAD, h1t, KPAD, x1, 512, b1, MROWS, 512, KPAD, KPAD);
  }

  // H2^T = (x1 @ W2)^T
  gemm_mfma<0, 0><<<dim3(2, 79), 256, 0, stream>>>(x1, 512, w2t, 512, h2t, KPAD, nullptr, MROWS, 256, 512, 512);

  // x2 = adj @ H2 + b2
  if (avail >= 5120000ull) {
    const int S2 = pick_split(avail, 5120000ull, 16);       // 10000x256 bf16/split
    const int chunk = ((157 + S2 - 1) / S2) * 64;
    gemm8p<<<dim3(1, 40, S2), 512, 0, stream>>>(adjb, KPAD, h2t, KPAD, Pb, MROWS, 256, KPAD, chunk);
    reduce_epi_kernel<1><<<1250, 256, 0, stream>>>(Pb, x2, b2, S2, 320000, 255u, 2560000ull);
  } else {
    gemm_mfma<1, 1><<<dim3(2, 79), 256, 0, stream>>>(adjb, KPAD, h2t, KPAD, x2, 256, b2, MROWS, 256, KPAD, KPAD);
  }

  // H3^T = (x2 @ W3)^T
  gemm_mfma<0, 0><<<dim3(1, 79), 256, 0, stream>>>(x2, 256, w3t, 256, h3t, KPAD, nullptr, MROWS, 128, 256, 256);

  // out = adj @ H3 + b3  (f32)
  if (avail >= 2560000ull) {
    const int S3 = pick_split(avail, 2560000ull, 16);       // 10000x128 bf16/split
    const int chunk = ((314 + S3 - 1) / S3) * 32;
    gemm_mfma<3, 0><<<dim3(1, 79, S3), 256, 0, stream>>>(adjb, KPAD, h3t, KPAD, Pb, 128, nullptr, MROWS, 128, KPAD, chunk);
    reduce_epi_kernel<3><<<625, 256, 0, stream>>>(Pb, out, b3, S3, 160000, 127u, 1280000ull);
  } else {
    gemm_mfma<2, 1><<<dim3(1, 79), 256, 0, stream>>>(adjb, KPAD, h3t, KPAD, out, 128, b3, MROWS, 128, KPAD, KPAD);
  }
}